// Round 1
// 171.930 us; speedup vs baseline: 1.0535x; 1.0535x over previous
//
#include <hip/hip_runtime.h>
#include <stdint.h>

// Problem constants
#define BB 4
#define CC 256
#define HH 96
#define WW 96
#define HP 98      // halo-padded spatial dim
#define CP 264     // k-stride per x in ush (528 B; measured near-conflict-free b128 frags)
#define XT 32      // x positions per block
#define YT 2       // y rows per block
#define XE 34      // staged x entries (32 + 2 halo)

typedef __bf16 bf16x8 __attribute__((ext_vector_type(8)));
typedef float f32x4 __attribute__((ext_vector_type(4)));
typedef float f32x16 __attribute__((ext_vector_type(16)));

__device__ __forceinline__ uint16_t f2bf(float f) {
    uint32_t u = __float_as_uint(f);
    u += 0x7FFFu + ((u >> 16) & 1u);   // round-to-nearest-even
    return (uint16_t)(u >> 16);
}

// ---------------------------------------------------------------------------
// Pre-kernel 1: cen (NCHW fp32) -> cenT [b][hy 98][hx 98][264] bf16 (halo=0 via
// prior memset). Block = (y, b, c-half): 25.6 KB LDS.
// ---------------------------------------------------------------------------
__global__ void transpose_cen(const float* __restrict__ cen, uint16_t* __restrict__ cenT) {
    const int y = blockIdx.x, b = blockIdx.y, ch = blockIdx.z, tid = threadIdx.x;
    __shared__ uint16_t ldsX[128 * 100];

    #pragma unroll
    for (int i = 0; i < 12; ++i) {
        int f = i * 256 + tid;            // 0..3071: 128 c x 24 xq
        int c = f / 24, xq = f % 24;
        float4 v = *(const float4*)(cen + ((((size_t)b * CC + ch * 128 + c) * HH + y) * WW + xq * 4));
        uint2 pk;
        pk.x = (uint32_t)f2bf(v.x) | ((uint32_t)f2bf(v.y) << 16);
        pk.y = (uint32_t)f2bf(v.z) | ((uint32_t)f2bf(v.w) << 16);
        *(uint2*)(&ldsX[c * 100 + xq * 4]) = pk;
    }
    __syncthreads();
    #pragma unroll
    for (int i = 0; i < 6; ++i) {
        int t = i * 256 + tid;            // 0..1535: 96 x * 16 cq
        int x = t % 96, cq = t / 96;
        uint32_t w0, w1, w2, w3;
        w0 = (uint32_t)ldsX[(cq * 8 + 0) * 100 + x] | ((uint32_t)ldsX[(cq * 8 + 1) * 100 + x] << 16);
        w1 = (uint32_t)ldsX[(cq * 8 + 2) * 100 + x] | ((uint32_t)ldsX[(cq * 8 + 3) * 100 + x] << 16);
        w2 = (uint32_t)ldsX[(cq * 8 + 4) * 100 + x] | ((uint32_t)ldsX[(cq * 8 + 5) * 100 + x] << 16);
        w3 = (uint32_t)ldsX[(cq * 8 + 6) * 100 + x] | ((uint32_t)ldsX[(cq * 8 + 7) * 100 + x] << 16);
        size_t o = (((size_t)b * HP + (y + 1)) * HP + (x + 1)) * CP + ch * 128 + cq * 8;
        *(uint4*)(cenT + o) = make_uint4(w0, w1, w2, w3);
    }
}

// ---------------------------------------------------------------------------
// Pre-kernel 2: W3 [9][256 n][256 k] fp32 -> W3bf [g][t 8][ks 16][m 32][kh 2][8]
// A-frag (32x32x16: lane m holds k = kh*8 + j) for (g,t,ks) = 1 KiB contiguous.
// ---------------------------------------------------------------------------
__global__ void cvt_w3(const float* __restrict__ W3, uint16_t* __restrict__ W3bf) {
    int e = (blockIdx.x * 256 + threadIdx.x) * 4;   // 0..589823
    int g = e >> 16, n = (e >> 8) & 255, k = e & 255;
    float4 v = *(const float4*)(W3 + e);
    uint2 pk;
    pk.x = (uint32_t)f2bf(v.x) | ((uint32_t)f2bf(v.y) << 16);
    pk.y = (uint32_t)f2bf(v.z) | ((uint32_t)f2bf(v.w) << 16);
    size_t o = (size_t)(((g * 8 + (n >> 5)) * 16 + (k >> 4)) * 512)
             + (n & 31) * 16 + ((k >> 3) & 1) * 8 + (k & 7);
    *(uint2*)(W3bf + o) = pk;
}

// ---------------------------------------------------------------------------
// Main kernel: grid (3 xt, 48 yt, 4 b) = 576 blocks, 256 thr (4 waves).
// Block tile: 64 positions (2 rows x 32 x) x 256 ch.
// Wave wv owns TWO ch-tiles (2wv, 2wv+1): per ks-step = 2 A-loads (L2) +
// 2 B-loads (LDS, each feeding 2 MFMAs) + 4 MFMAs on 4 independent acc chains.
// -> halves LDS B-traffic per MFMA (was 8 waves reading identical frags),
//    doubles per-wave MFMA ILP, and 4-wave blocks fit 3 blocks/CU
//    (LDS 3x38KB=114KB, VGPR cap 170) so all 576 blocks are co-resident.
// Norm: 32 in-lane FMA + shfl_xor(32) + ping-pong ldsP -> ONE barrier per g.
// ---------------------------------------------------------------------------
__global__ __launch_bounds__(256, 3)
void ecm_main(const float* __restrict__ cen, const uint16_t* __restrict__ cenT,
              const uint16_t* __restrict__ W3bf, float* __restrict__ out) {
    const int tid = threadIdx.x;
    const int wv = tid >> 6, lane = tid & 63, col = lane & 31, kh = lane >> 5;
    const int x0 = blockIdx.x * XT, y0 = blockIdx.y * YT, b = blockIdx.z;

    __shared__ __align__(16) uint16_t ldsA[YT * XE * CP];   // 35,904 B
    __shared__ __align__(16) float ldsP[2][64][4];          // ping-pong norm partials (2 KB)

    // g processed in dy-groups; dgOrd[idx] = reference g index, dx = idx%3 - 1.
    const int dgOrd[9] = {0, 1, 2, 7, 8, 3, 6, 5, 4};

    // wave owns ch-tiles 2wv and 2wv+1 (adjacent 16-KB A-streams per g)
    const uint16_t* wbA = W3bf + (size_t)(2 * wv) * (16 * 512) + col * 16 + kh * 8;
    f32x16 finA0 = {}, finA1 = {}, finB0 = {}, finB1 = {};

    #pragma unroll 1
    for (int idx = 0; idx < 9; ++idx) {
        const int g = dgOrd[idx], dg = idx / 3, dx = idx % 3 - 1;

        if (idx % 3 == 0) {
            // All waves passed the previous g's barrier => their ldsA reads are
            // done (reads precede each wave's ldsP write, which precedes that
            // barrier). Safe to restage without an extra leading barrier.
            for (int r = 0; r < YT; ++r) {
                const uint4* gs = (const uint4*)(cenT + (((size_t)b * HP + (y0 + dg + r)) * HP + x0) * CP);
                uint4* ls = (uint4*)(ldsA + r * XE * CP);
                for (int c = tid; c < XE * CP / 8; c += 256) ls[c] = gs[c];
            }
            __syncthreads();
        }

        const uint16_t* wgA = wbA + (size_t)g * 65536;
        const uint16_t* wgB = wgA + 16 * 512;                 // second ch-tile
        const int a0 = (col + dx + 1) * CP + kh * 8;
        const int a1 = a0 + XE * CP;

        f32x16 aA0 = {}, aA1 = {}, aB0 = {}, aB1 = {};
        bf16x8 wfA = *(const bf16x8*)(wgA);
        bf16x8 wfB = *(const bf16x8*)(wgB);
        bf16x8 b0 = *(const bf16x8*)(ldsA + a0);
        bf16x8 b1 = *(const bf16x8*)(ldsA + a1);
        #pragma unroll
        for (int ks = 0; ks < 15; ++ks) {
            bf16x8 wnA = *(const bf16x8*)(wgA + (ks + 1) * 512);
            bf16x8 wnB = *(const bf16x8*)(wgB + (ks + 1) * 512);
            bf16x8 bn0 = *(const bf16x8*)(ldsA + a0 + (ks + 1) * 16);
            bf16x8 bn1 = *(const bf16x8*)(ldsA + a1 + (ks + 1) * 16);
            aA0 = __builtin_amdgcn_mfma_f32_32x32x16_bf16(wfA, b0, aA0, 0, 0, 0);
            aB0 = __builtin_amdgcn_mfma_f32_32x32x16_bf16(wfB, b0, aB0, 0, 0, 0);
            aA1 = __builtin_amdgcn_mfma_f32_32x32x16_bf16(wfA, b1, aA1, 0, 0, 0);
            aB1 = __builtin_amdgcn_mfma_f32_32x32x16_bf16(wfB, b1, aB1, 0, 0, 0);
            wfA = wnA; wfB = wnB; b0 = bn0; b1 = bn1;
        }
        aA0 = __builtin_amdgcn_mfma_f32_32x32x16_bf16(wfA, b0, aA0, 0, 0, 0);
        aB0 = __builtin_amdgcn_mfma_f32_32x32x16_bf16(wfB, b0, aB0, 0, 0, 0);
        aA1 = __builtin_amdgcn_mfma_f32_32x32x16_bf16(wfA, b1, aA1, 0, 0, 0);
        aB1 = __builtin_amdgcn_mfma_f32_32x32x16_bf16(wfB, b1, aB1, 0, 0, 0);

        // Per-position ||Y||^2 partial over this wave's 64 ch (both tiles).
        float s0 = 0.f, s1 = 0.f;
        #pragma unroll
        for (int r = 0; r < 16; ++r) {
            s0 += aA0[r] * aA0[r] + aB0[r] * aB0[r];
            s1 += aA1[r] * aA1[r] + aB1[r] * aB1[r];
        }
        s0 += __shfl_xor(s0, 32, 64);
        s1 += __shfl_xor(s1, 32, 64);
        if (kh == 0) { ldsP[idx & 1][col][wv] = s0; ldsP[idx & 1][32 + col][wv] = s1; }
        __syncthreads();   // the ONLY barrier per g (ping-pong covers WAR)

        f32x4 pa = *(const f32x4*)&ldsP[idx & 1][col][0];
        f32x4 qa = *(const f32x4*)&ldsP[idx & 1][32 + col][0];
        float n0 = pa[0] + pa[1] + pa[2] + pa[3];
        float n1 = qa[0] + qa[1] + qa[2] + qa[3];
        const float sgn = (g == 8) ? 1.f : -1.f;
        float sc0 = sgn / fmaxf(sqrtf(n0), 1e-12f);
        float sc1 = sgn / fmaxf(sqrtf(n1), 1e-12f);
        #pragma unroll
        for (int r = 0; r < 16; ++r) {
            finA0[r] += aA0[r] * sc0; finB0[r] += aB0[r] * sc0;
            finA1[r] += aA1[r] * sc1; finB1[r] += aB1[r] * sc1;
        }
    }

    // Epilogue: out = fin + cen. D row->ch: (reg&3) + 8*(reg>>2) + 4*kh (+64*wv / +32 tileB).
    #pragma unroll
    for (int r = 0; r < 16; ++r) {
        int chA = wv * 64 + (r & 3) + 8 * (r >> 2) + 4 * kh;
        size_t oA0 = (((size_t)b * CC + chA) * HH + y0) * WW + (x0 + col);
        size_t oA1 = oA0 + WW;
        out[oA0] = finA0[r] + cen[oA0];
        out[oA1] = finA1[r] + cen[oA1];
        size_t oB0 = oA0 + (size_t)32 * HH * WW;
        size_t oB1 = oB0 + WW;
        out[oB0] = finB0[r] + cen[oB0];
        out[oB1] = finB1[r] + cen[oB1];
    }
}

extern "C" void kernel_launch(void* const* d_in, const int* in_sizes, int n_in,
                              void* d_out, int out_size, void* d_ws, size_t ws_size,
                              hipStream_t stream) {
    const float* cen = (const float*)d_in[0];
    // d_in[1] = W1, d_in[2] = W2: dead code (softmax over size-1 axis == 1.0)
    const float* W3 = (const float*)d_in[3];
    float* out = (float*)d_out;

    uint16_t* cenT = (uint16_t*)d_ws;                         // [4][98][98][264] bf16
    const size_t cenT_elems = (size_t)BB * HP * HP * CP;
    uint16_t* W3bf = cenT + cenT_elems;                       // [9][8][16][512] bf16

    hipMemsetAsync(d_ws, 0, cenT_elems * sizeof(uint16_t), stream);   // zero halos
    transpose_cen<<<dim3(HH, BB, 2), 256, 0, stream>>>(cen, cenT);
    cvt_w3<<<576, 256, 0, stream>>>(W3, W3bf);
    ecm_main<<<dim3(3, 48, 4), 256, 0, stream>>>(cen, cenT, W3bf, out);
}